// Round 14
// baseline (386.811 us; speedup 1.0000x reference)
//
#include <hip/hip_runtime.h>
#include <math.h>

// ChebNet: 4 layers of ChebConv(K=3) + sigmoid.
// norm = -D^{-1/2} A D^{-1/2} (self loops removed)
// per layer: t1 = L@h ; U = L@t1 ; out = sigmoid(h@(W0-W2) + t1@W1 + U@(2*W2) + b)
//
// R1: atomic scatter -> CSR gather; 10.06ms -> 1.28ms
// R2: register-tiled gemm3, fused CSR build; -> 0.949ms
// R3: packed edges, layer-3 commute form; -> 0.823ms
// R4: bf16 gathers, t2 folded into weights; -> 0.660ms
// R5: two-level partition CSR build; -> 0.519ms
// R6: zero-global-atomic CSR build, bf16-only features; -> 0.494ms
// R7: all GEMMs -> MFMA; -> 0.397ms
// R8: REGRESSED (nt STORES write-through per-store, CHUNK 8192 starved).
// R9: revert; NPP 512; -> 0.397ms
// R10: XCD chunk swizzle + 4B packed epk; -> 0.360ms
// R11: REGRESSED (NPP 1024); reverted.
// R12: CHUNK 4096; -> 0.354ms
// R13: nt LOADS for read-once edge streams (epk/bufC/bufR) so L2 keeps the
//      gather table; count merged into init (independent work overlaps).

typedef __attribute__((ext_vector_type(8))) short short8_t;
typedef __attribute__((ext_vector_type(4))) short short4_t;
typedef __attribute__((ext_vector_type(4))) float f32x4;

#define NPP 512          // nodes per partition
#define FSH 9            // log2(NPP)
#define CHUNK 4096       // edges per block in count/scatter passes
#define NXCD 8

__device__ __forceinline__ float bf2f(short s) {
    return __int_as_float(((int)(unsigned short)s) << 16);
}
__device__ __forceinline__ short f2bf(float f) {  // round-to-nearest-even
    unsigned u = __float_as_uint(f);
    return (short)((u + 0x7FFFu + ((u >> 16) & 1u)) >> 16);
}

// Bijective blockIdx -> chunk map grouping consecutive chunks on one XCD
__device__ __forceinline__ int chunk_of_block(int bid, int B) {
    int xcd = bid & (NXCD - 1);
    int i = bid >> 3;
    int q = B >> 3, r = B & (NXCD - 1);
    return (xcd < r) ? xcd * (q + 1) + i : r * (q + 1) + (xcd - r) * q + i;
}

// edge decode: packed = (norm_top15 << 17) | src_row   (requires n < 2^17)
__device__ __forceinline__ int epk_row(unsigned u) { return (int)(u & 0x1FFFFu); }
__device__ __forceinline__ float epk_val(unsigned u) {
    return __uint_as_float((u >> 17) << 17);
}

// ---------------- init (x->bf16 + weight pre-pack) fused with count ----------------
// B-fragment layout for mfma_f32_16x16x32_bf16: lane holds B[k][col] with
// col = lane&15, k = (lane>>4)*8 + e.

__global__ __launch_bounds__(256) void init_count_kernel(
        const float* __restrict__ in, short* __restrict__ out, long m,
        const float* __restrict__ W1, const float* __restrict__ W2,
        const float* __restrict__ W3, const float* __restrict__ W4,
        short8_t* __restrict__ wpk1, short8_t* __restrict__ wpk2,
        short8_t* __restrict__ wpkm, short8_t* __restrict__ wpk4,
        const int* __restrict__ row, const int* __restrict__ col,
        int* __restrict__ cntC, int* __restrict__ cntR,
        int initB, int P, int B, int E) {
    __shared__ int hc[2][256], hr[2][256];
    if (blockIdx.x >= initB) {
        // ---- count branch ----
        int cbid = blockIdx.x - initB;
        for (int i = threadIdx.x; i < P; i += 256) {
            hc[0][i] = 0; hc[1][i] = 0; hr[0][i] = 0; hr[1][i] = 0;
        }
        __syncthreads();
        int chunk = chunk_of_block(cbid, B);
        int cp = threadIdx.x & 1;
        int base = chunk * CHUNK;
        int lim = min(E, base + CHUNK);
        for (int e = base + threadIdx.x; e < lim; e += 256) {
            atomicAdd(&hc[cp][col[e] >> FSH], 1);
            atomicAdd(&hr[cp][row[e] >> FSH], 1);
        }
        __syncthreads();
        long o = (long)chunk * P;
        for (int i = threadIdx.x; i < P; i += 256) {
            cntC[o + i] = hc[0][i] + hc[1][i];
            cntR[o + i] = hr[0][i] + hr[1][i];
        }
        return;
    }
    // ---- init branch ----
    long gi = (long)blockIdx.x * 256 + threadIdx.x;
    long i4 = gi * 4;
    if (i4 < m) {
        float4 v = *reinterpret_cast<const float4*>(in + i4);
        short4_t s;
        s[0] = f2bf(v.x); s[1] = f2bf(v.y); s[2] = f2bf(v.z); s[3] = f2bf(v.w);
        *reinterpret_cast<short4_t*>(out + i4) = s;
    }
    int idx = (int)gi;
    if (idx >= 4032) return;
    short8_t o;
    if (idx < 3072) {  // gemm3 packs for W1 / W2 (64->64)
        const float* W = (idx < 1536) ? W1 : W2;
        int f = (idx < 1536) ? idx : idx - 1536;
        int lane = f & 63, ct = (f >> 6) & 3, s = f >> 8;
        int li = lane & 15, lg = lane >> 4;
        int p = s >> 1;
        int cidx = ct * 16 + li;
#pragma unroll
        for (int e = 0; e < 8; ++e) {
            int k = (s & 1) * 32 + lg * 8 + e;
            int base = k * 64 + cidx;
            float v = (p == 0) ? W[base] - W[8192 + base]
                    : (p == 1) ? W[4096 + base]
                               : 2.0f * W[8192 + base];
            o[e] = f2bf(v);
        }
        ((idx < 1536) ? wpk1 : wpk2)[f] = o;
    } else if (idx < 3840) {  // gemm_multi pack for W3 (64->3x32)
        int f = idx - 3072;
        int lane = f & 63, q = f >> 6;
        int s = q / 6, ct = q % 6;
        int li = lane & 15, lg = lane >> 4;
        int g = ct >> 1;
        int cl = (ct & 1) * 16 + li;
#pragma unroll
        for (int e = 0; e < 8; ++e) {
            int k = s * 32 + lg * 8 + e;
            int base = k * 32 + cl;
            float v = (g == 0) ? W3[base] - W3[4096 + base]
                    : (g == 1) ? W3[2048 + base]
                               : W3[4096 + base];
            o[e] = f2bf(v);
        }
        wpkm[f] = o;
    } else {  // gemm4 pack for W4 (32->16)
        int f = idx - 3840;
        int lane = f & 63, s = f >> 6;
        int li = lane & 15, lg = lane >> 4;
#pragma unroll
        for (int e = 0; e < 8; ++e) {
            int k = lg * 8 + e;
            int base = k * 16 + li;
            float v = (s == 0) ? W4[base] - W4[1024 + base]
                    : (s == 1) ? W4[512 + base]
                               : 2.0f * W4[1024 + base];
            o[e] = f2bf(v);
        }
        wpk4[f] = o;
    }
}

// ---------------- CSR build (zero global atomics) ----------------

__global__ __launch_bounds__(256) void colscan_kernel(
        int* __restrict__ cntC, int* __restrict__ cntR,
        int* __restrict__ ptotC, int* __restrict__ ptotR, int P, int B) {
    int bid = blockIdx.x;
    int* m; int* ptot; int p;
    if (bid < P) { m = cntC; ptot = ptotC; p = bid; }
    else         { m = cntR; ptot = ptotR; p = bid - P; }
    __shared__ int sh[256];
    int run = 0;
    for (int b0 = 0; b0 < B; b0 += 256) {
        int b = b0 + threadIdx.x;
        int v = (b < B) ? m[(long)b * P + p] : 0;
        sh[threadIdx.x] = v;
        __syncthreads();
        for (int o = 1; o < 256; o <<= 1) {
            int t = (threadIdx.x >= o) ? sh[threadIdx.x - o] : 0;
            __syncthreads();
            sh[threadIdx.x] += t;
            __syncthreads();
        }
        if (b < B) m[(long)b * P + p] = run + sh[threadIdx.x] - v;
        run += sh[255];
        __syncthreads();
    }
    if (threadIdx.x == 0) ptot[p] = run;
}

__global__ __launch_bounds__(256) void pscan_kernel(
        const int* __restrict__ ptotC, const int* __restrict__ ptotR,
        int* __restrict__ pofsC, int* __restrict__ pofsR,
        int* __restrict__ ofs, int P, int n, int E) {
    __shared__ int sh[256];
    int tid = threadIdx.x;
    int v = (tid < P) ? ptotC[tid] : 0;
    sh[tid] = v;
    __syncthreads();
    for (int o = 1; o < 256; o <<= 1) {
        int t = (tid >= o) ? sh[tid - o] : 0;
        __syncthreads();
        sh[tid] += t;
        __syncthreads();
    }
    if (tid < P) pofsC[tid] = sh[tid] - v;
    if (tid == 0) pofsC[P] = E;
    __syncthreads();
    v = (tid < P) ? ptotR[tid] : 0;
    sh[tid] = v;
    __syncthreads();
    for (int o = 1; o < 256; o <<= 1) {
        int t = (tid >= o) ? sh[tid - o] : 0;
        __syncthreads();
        sh[tid] += t;
        __syncthreads();
    }
    if (tid < P) pofsR[tid] = sh[tid] - v;
    if (tid == 0) { pofsR[P] = E; ofs[n] = E; }
}

// bufC: (finec(9b) << 23 | row(23b), w_bits)   bufR: finer(9b)<<23 | (w>>9)

__global__ __launch_bounds__(256) void scatter_kernel(
        const int* __restrict__ row, const int* __restrict__ col,
        const float* __restrict__ ew,
        const int* __restrict__ cntC, const int* __restrict__ cntR,
        const int* __restrict__ pofsC, const int* __restrict__ pofsR,
        int2* __restrict__ bufC, unsigned* __restrict__ bufR, int P, int E) {
    __shared__ int hc[256], hr[256];
    int chunk = chunk_of_block(blockIdx.x, gridDim.x);
    long o = (long)chunk * P;
    for (int i = threadIdx.x; i < P; i += 256) {
        hc[i] = pofsC[i] + cntC[o + i];
        hr[i] = pofsR[i] + cntR[o + i];
    }
    __syncthreads();
    int base = chunk * CHUNK;
    int lim = min(E, base + CHUNK);
    for (int e = base + threadIdx.x; e < lim; e += 256) {
        int r = row[e], c = col[e];
        float w = (r == c) ? 0.0f : ew[e];
        unsigned wb = __float_as_uint(w);
        int pc = atomicAdd(&hc[c >> FSH], 1);
        bufC[pc] = make_int2((int)(((unsigned)(c & (NPP - 1)) << 23) | (unsigned)r), (int)wb);
        int pr = atomicAdd(&hr[r >> FSH], 1);
        bufR[pr] = ((unsigned)(r & (NPP - 1)) << 23) | (wb >> 9);
    }
}

__global__ __launch_bounds__(512) void dinv_kernel(
        const unsigned* __restrict__ bufR, const int* __restrict__ rofs,
        float* __restrict__ dinv, int n) {
    int p = blockIdx.x;
    __shared__ float s[NPP];
    s[threadIdx.x] = 0.0f;
    __syncthreads();
    int beg = rofs[p], end = rofs[p + 1];
    for (int k = beg + threadIdx.x; k < end; k += 512) {
        unsigned u = __builtin_nontemporal_load(&bufR[k]);
        atomicAdd(&s[u >> 23], __uint_as_float((u & 0x7FFFFFu) << 9));
    }
    __syncthreads();
    int node = (p << FSH) + threadIdx.x;
    if (node < n) {
        float d = s[threadIdx.x];
        dinv[node] = d > 0.0f ? rsqrtf(d) : 0.0f;
    }
}

__global__ __launch_bounds__(512) void fine_csr_kernel(
        const int2* __restrict__ bufC, const int* __restrict__ pofs,
        const float* __restrict__ dinv, int* __restrict__ ofs,
        unsigned* __restrict__ epk, int n) {
    int p = blockIdx.x;
    int tid = threadIdx.x;
    __shared__ int hist[NPP];
    __shared__ int sc[NPP];
    __shared__ float dc[NPP];
    hist[tid] = 0;
    int node = (p << FSH) + tid;
    dc[tid] = (node < n) ? dinv[node] : 0.0f;
    __syncthreads();
    int beg = pofs[p], end = pofs[p + 1];
    for (int k = beg + tid; k < end; k += 512) {
        long long ll = __builtin_nontemporal_load(
            reinterpret_cast<const long long*>(&bufC[k]));
        atomicAdd(&hist[((unsigned)(int)ll) >> 23], 1);
    }
    __syncthreads();
    int v = hist[tid];
    sc[tid] = v;
    __syncthreads();
    for (int o = 1; o < 512; o <<= 1) {
        int t = (tid >= o) ? sc[tid - o] : 0;
        __syncthreads();
        sc[tid] += t;
        __syncthreads();
    }
    int mybase = beg + sc[tid] - v;  // exclusive
    if (node < n) ofs[node] = mybase;
    hist[tid] = mybase;  // becomes cursor
    __syncthreads();
    for (int k = beg + tid; k < end; k += 512) {
        union { long long ll; int2 i2; } u;
        u.ll = __builtin_nontemporal_load(
            reinterpret_cast<const long long*>(&bufC[k]));
        unsigned key = (unsigned)u.i2.x;
        int fc = key >> 23;
        int r = (int)(key & 0x7FFFFFu);
        float w = __int_as_float(u.i2.y);
        float nrm = -dinv[r] * w * dc[fc];
        unsigned nb = __float_as_uint(nrm);
        unsigned n15 = (nb + 0xFFFFu + ((nb >> 17) & 1u)) >> 17;  // RNE top-15
        int pos = atomicAdd(&hist[fc], 1);
        epk[pos] = (n15 << 17) | (unsigned)r;  // requires n < 2^17
    }
}

// ---------------- aggregation (bf16 gather, fp32 accumulate, bf16 out) ----------------

template <int D>
__global__ __launch_bounds__(256) void agg_kernel(
        const int* __restrict__ ofs, const unsigned* __restrict__ epk,
        const short* __restrict__ tb, short* __restrict__ outb, int n) {
    constexpr int LPN = D / 8;
    int idx = blockIdx.x * 256 + threadIdx.x;
    int node = idx / LPN;
    int l = idx % LPN;
    if (node >= n) return;
    int beg = ofs[node], end = ofs[node + 1];
    float a[8] = {0.f, 0.f, 0.f, 0.f, 0.f, 0.f, 0.f, 0.f};
    const short* tc = tb + l * 8;
    int k = beg;
    for (; k + 8 <= end; k += 8) {
        unsigned ev[8];
        short8_t xv[8];
#pragma unroll
        for (int u = 0; u < 8; ++u) ev[u] = __builtin_nontemporal_load(&epk[k + u]);
#pragma unroll
        for (int u = 0; u < 8; ++u)
            xv[u] = *reinterpret_cast<const short8_t*>(tc + (long)epk_row(ev[u]) * D);
#pragma unroll
        for (int u = 0; u < 8; ++u) {
            float v = epk_val(ev[u]);
#pragma unroll
            for (int j = 0; j < 8; ++j) a[j] = fmaf(v, bf2f(xv[u][j]), a[j]);
        }
    }
    for (; k + 4 <= end; k += 4) {
        unsigned ev[4];
        short8_t xv[4];
#pragma unroll
        for (int u = 0; u < 4; ++u) ev[u] = __builtin_nontemporal_load(&epk[k + u]);
#pragma unroll
        for (int u = 0; u < 4; ++u)
            xv[u] = *reinterpret_cast<const short8_t*>(tc + (long)epk_row(ev[u]) * D);
#pragma unroll
        for (int u = 0; u < 4; ++u) {
            float v = epk_val(ev[u]);
#pragma unroll
            for (int j = 0; j < 8; ++j) a[j] = fmaf(v, bf2f(xv[u][j]), a[j]);
        }
    }
    for (; k < end; ++k) {
        unsigned e0 = __builtin_nontemporal_load(&epk[k]);
        short8_t x0 = *reinterpret_cast<const short8_t*>(tc + (long)epk_row(e0) * D);
        float v = epk_val(e0);
#pragma unroll
        for (int j = 0; j < 8; ++j) a[j] = fmaf(v, bf2f(x0[j]), a[j]);
    }
    short8_t s;
#pragma unroll
    for (int j = 0; j < 8; ++j) s[j] = f2bf(a[j]);
    *reinterpret_cast<short8_t*>(outb + (long)node * D + l * 8) = s;
}

// Dual agg for layer 3: tb [n][64] = [P1|P2] bf16; lanes 0-3 -> Q1b, 4-7 -> Q2b.

__global__ __launch_bounds__(256) void agg_dual_kernel(
        const int* __restrict__ ofs, const unsigned* __restrict__ epk,
        const short* __restrict__ tb, short* __restrict__ Q1b,
        short* __restrict__ Q2b, int n) {
    int idx = blockIdx.x * 256 + threadIdx.x;
    int node = idx >> 3;
    int l = idx & 7;
    if (node >= n) return;
    int beg = ofs[node], end = ofs[node + 1];
    float a[8] = {0.f, 0.f, 0.f, 0.f, 0.f, 0.f, 0.f, 0.f};
    const short* tc = tb + l * 8;
    int k = beg;
    for (; k + 8 <= end; k += 8) {
        unsigned ev[8];
        short8_t xv[8];
#pragma unroll
        for (int u = 0; u < 8; ++u) ev[u] = __builtin_nontemporal_load(&epk[k + u]);
#pragma unroll
        for (int u = 0; u < 8; ++u)
            xv[u] = *reinterpret_cast<const short8_t*>(tc + (long)epk_row(ev[u]) * 64);
#pragma unroll
        for (int u = 0; u < 8; ++u) {
            float v = epk_val(ev[u]);
#pragma unroll
            for (int j = 0; j < 8; ++j) a[j] = fmaf(v, bf2f(xv[u][j]), a[j]);
        }
    }
    for (; k + 4 <= end; k += 4) {
        unsigned ev[4];
        short8_t xv[4];
#pragma unroll
        for (int u = 0; u < 4; ++u) ev[u] = __builtin_nontemporal_load(&epk[k + u]);
#pragma unroll
        for (int u = 0; u < 4; ++u)
            xv[u] = *reinterpret_cast<const short8_t*>(tc + (long)epk_row(ev[u]) * 64);
#pragma unroll
        for (int u = 0; u < 4; ++u) {
            float v = epk_val(ev[u]);
#pragma unroll
            for (int j = 0; j < 8; ++j) a[j] = fmaf(v, bf2f(xv[u][j]), a[j]);
        }
    }
    for (; k < end; ++k) {
        unsigned e0 = __builtin_nontemporal_load(&epk[k]);
        short8_t x0 = *reinterpret_cast<const short8_t*>(tc + (long)epk_row(e0) * 64);
        float v = epk_val(e0);
#pragma unroll
        for (int j = 0; j < 8; ++j) a[j] = fmaf(v, bf2f(x0[j]), a[j]);
    }
    short* ob = (l < 4) ? Q1b : Q2b;
    long o = (long)node * 32 + (l & 3) * 8;
    short8_t s;
#pragma unroll
    for (int j = 0; j < 8; ++j) s[j] = f2bf(a[j]);
    *reinterpret_cast<short8_t*>(ob + o) = s;
}

// Final layer-3 agg: acc = L@Q2 gather; out = sigmoid(S + Q1 + 2*acc) (bf16).

__global__ __launch_bounds__(256) void agg_fin_kernel(
        const int* __restrict__ ofs, const unsigned* __restrict__ epk,
        const short* __restrict__ Q2b, const float* __restrict__ S,
        const short* __restrict__ Q1b, short* __restrict__ outb, int n) {
    int idx = blockIdx.x * 256 + threadIdx.x;
    int node = idx >> 2;
    int l = idx & 3;
    if (node >= n) return;
    int beg = ofs[node], end = ofs[node + 1];
    float a[8] = {0.f, 0.f, 0.f, 0.f, 0.f, 0.f, 0.f, 0.f};
    const short* tc = Q2b + l * 8;
    int k = beg;
    for (; k + 4 <= end; k += 4) {
        unsigned ev[4];
        short8_t xv[4];
#pragma unroll
        for (int u = 0; u < 4; ++u) ev[u] = __builtin_nontemporal_load(&epk[k + u]);
#pragma unroll
        for (int u = 0; u < 4; ++u)
            xv[u] = *reinterpret_cast<const short8_t*>(tc + (long)epk_row(ev[u]) * 32);
#pragma unroll
        for (int u = 0; u < 4; ++u) {
            float v = epk_val(ev[u]);
#pragma unroll
            for (int j = 0; j < 8; ++j) a[j] = fmaf(v, bf2f(xv[u][j]), a[j]);
        }
    }
    for (; k < end; ++k) {
        unsigned e0 = __builtin_nontemporal_load(&epk[k]);
        short8_t x0 = *reinterpret_cast<const short8_t*>(tc + (long)epk_row(e0) * 32);
        float v = epk_val(e0);
#pragma unroll
        for (int j = 0; j < 8; ++j) a[j] = fmaf(v, bf2f(x0[j]), a[j]);
    }
    long o = (long)node * 32 + l * 8;
    float4 s0 = *reinterpret_cast<const float4*>(S + o);
    float4 s1 = *reinterpret_cast<const float4*>(S + o + 4);
    short8_t q1 = *reinterpret_cast<const short8_t*>(Q1b + o);
    float sv[8] = {s0.x, s0.y, s0.z, s0.w, s1.x, s1.y, s1.z, s1.w};
    short8_t r;
#pragma unroll
    for (int j = 0; j < 8; ++j) {
        float z = sv[j] + bf2f(q1[j]) + 2.0f * a[j];
        r[j] = f2bf(1.0f / (1.0f + expf(-z)));
    }
    *reinterpret_cast<short8_t*>(outb + o) = r;
}

// ---------------- MFMA GEMMs ----------------

__global__ __launch_bounds__(256) void gemm3_mfma(
        const short* __restrict__ t0b, const short* __restrict__ t1b,
        const short* __restrict__ t2b, const short8_t* __restrict__ wpk,
        const float* __restrict__ b, short* __restrict__ outb, int n) {
    const int tid = threadIdx.x;
    const int wave = tid >> 6;
    const int lane = tid & 63;
    const int li = lane & 15;
    const int lg = lane >> 4;

    short8_t bfr[6][4];
#pragma unroll
    for (int s = 0; s < 6; ++s)
#pragma unroll
        for (int ct = 0; ct < 4; ++ct)
            bfr[s][ct] = wpk[(s * 4 + ct) * 64 + lane];

    float bias_v[4];
#pragma unroll
    for (int ct = 0; ct < 4; ++ct) bias_v[ct] = b[ct * 16 + li];

#pragma unroll
    for (int t = 0; t < 2; ++t) {
        int r0 = blockIdx.x * 128 + wave * 32 + t * 16;
        if (r0 >= n) continue;
        int rA = r0 + li;
        if (rA >= n) rA = n - 1;
        f32x4 acc[4] = {{0.f, 0.f, 0.f, 0.f}, {0.f, 0.f, 0.f, 0.f},
                        {0.f, 0.f, 0.f, 0.f}, {0.f, 0.f, 0.f, 0.f}};
#pragma unroll
        for (int s = 0; s < 6; ++s) {
            const short* src = (s < 2) ? t0b : (s < 4) ? t1b : t2b;
            int k = (s & 1) * 32 + lg * 8;
            short8_t a = *reinterpret_cast<const short8_t*>(src + (long)rA * 64 + k);
#pragma unroll
            for (int ct = 0; ct < 4; ++ct)
                acc[ct] = __builtin_amdgcn_mfma_f32_16x16x32_bf16(a, bfr[s][ct], acc[ct], 0, 0, 0);
        }
#pragma unroll
        for (int ct = 0; ct < 4; ++ct) {
#pragma unroll
            for (int reg = 0; reg < 4; ++reg) {
                int row = r0 + lg * 4 + reg;
                if (row < n) {
                    float z = acc[ct][reg] + bias_v[ct];
                    float res = 1.0f / (1.0f + expf(-z));
                    outb[(long)row * 64 + ct * 16 + li] = f2bf(res);
                }
            }
        }
    }
}

__global__ __launch_bounds__(256) void gemm_multi_mfma(
        const short* __restrict__ hb, const short8_t* __restrict__ wpk,
        const float* __restrict__ b, short* __restrict__ P12b,
        float* __restrict__ S, int n) {
    const int tid = threadIdx.x;
    const int wave = tid >> 6;
    const int lane = tid & 63;
    const int li = lane & 15;
    const int lg = lane >> 4;

    short8_t bfr[2][6];
#pragma unroll
    for (int s = 0; s < 2; ++s)
#pragma unroll
        for (int ct = 0; ct < 6; ++ct)
            bfr[s][ct] = wpk[(s * 6 + ct) * 64 + lane];

    float bS0 = b[li], bS1 = b[16 + li];

#pragma unroll
    for (int t = 0; t < 2; ++t) {
        int r0 = blockIdx.x * 128 + wave * 32 + t * 16;
        if (r0 >= n) continue;
        int rA = r0 + li;
        if (rA >= n) rA = n - 1;
        f32x4 acc[6] = {{0.f, 0.f, 0.f, 0.f}, {0.f, 0.f, 0.f, 0.f},
                        {0.f, 0.f, 0.f, 0.f}, {0.f, 0.f, 0.f, 0.f},
                        {0.f, 0.f, 0.f, 0.f}, {0.f, 0.f, 0.f, 0.f}};
#pragma unroll
        for (int s = 0; s < 2; ++s) {
            int k = s * 32 + lg * 8;
            short8_t a = *reinterpret_cast<const short8_t*>(hb + (long)rA * 64 + k);
#pragma unroll
            for (int ct = 0; ct < 6; ++ct)
                acc[ct] = __builtin_amdgcn_mfma_f32_16x16x32_bf16(a, bfr[s][ct], acc[ct], 0, 0, 0);
        }
#pragma unroll
        for (int ct = 0; ct < 6; ++ct) {
            int g = ct >> 1;
            int cl = (ct & 1) * 16 + li;
#pragma unroll
            for (int reg = 0; reg < 4; ++reg) {
                int row = r0 + lg * 4 + reg;
                if (row >= n) continue;
                float v = acc[ct][reg];
                if (g == 0) {
                    S[(long)row * 32 + cl] = v + ((ct & 1) ? bS1 : bS0);
                } else if (g == 1) {
                    P12b[(long)row * 64 + cl] = f2bf(v);
                } else {
                    P12b[(long)row * 64 + 32 + cl] = f2bf(v);
                }
            }
        }
    }
}

__global__ __launch_bounds__(256) void gemm4_mfma(
        const short* __restrict__ t0b, const short* __restrict__ t1b,
        const short* __restrict__ t2b, const short8_t* __restrict__ wpk,
        const float* __restrict__ b, float* __restrict__ out, int n) {
    const int tid = threadIdx.x;
    const int wave = tid >> 6;
    const int lane = tid & 63;
    const int li = lane & 15;
    const int lg = lane >> 4;

    short8_t bfr[3];
#pragma unroll
    for (int s = 0; s < 3; ++s) bfr[s] = wpk[s * 64 + lane];

    float bias_v = b[li];

#pragma unroll
    for (int t = 0; t < 2; ++t) {
        int r0 = blockIdx.x * 128 + wave * 32 + t * 16;
        if (r0 >= n) continue;
        int rA = r0 + li;
        if (rA >= n) rA = n - 1;
        f32x4 acc = {0.f, 0.f, 0.f, 0.f};
        int k = lg * 8;
        short8_t a0 = *reinterpret_cast<const short8_t*>(t0b + (long)rA * 32 + k);
        acc = __builtin_amdgcn_mfma_f32_16x16x32_bf16(a0, bfr[0], acc, 0, 0, 0);
        short8_t a1 = *reinterpret_cast<const short8_t*>(t1b + (long)rA * 32 + k);
        acc = __builtin_amdgcn_mfma_f32_16x16x32_bf16(a1, bfr[1], acc, 0, 0, 0);
        short8_t a2 = *reinterpret_cast<const short8_t*>(t2b + (long)rA * 32 + k);
        acc = __builtin_amdgcn_mfma_f32_16x16x32_bf16(a2, bfr[2], acc, 0, 0, 0);
#pragma unroll
        for (int reg = 0; reg < 4; ++reg) {
            int row = r0 + lg * 4 + reg;
            if (row < n) {
                float z = acc[reg] + bias_v;
                out[(long)row * 16 + li] = 1.0f / (1.0f + expf(-z));
            }
        }
    }
}

// ---------------- host side ----------------

static inline int ceil_div_l(long a, long b) { return (int)((a + b - 1) / b); }

extern "C" void kernel_launch(void* const* d_in, const int* in_sizes, int n_in,
                              void* d_out, int out_size, void* d_ws, size_t ws_size,
                              hipStream_t stream) {
    const float* x  = (const float*)d_in[0];
    const int*   ei = (const int*)d_in[1];
    const float* ew = (const float*)d_in[2];
    const float* W1 = (const float*)d_in[3];  const float* b1 = (const float*)d_in[4];
    const float* W2 = (const float*)d_in[5];  const float* b2 = (const float*)d_in[6];
    const float* W3 = (const float*)d_in[7];  const float* b3 = (const float*)d_in[8];
    const float* W4 = (const float*)d_in[9];  const float* b4 = (const float*)d_in[10];

    const int E = in_sizes[2];          // 1,600,000
    const int n = in_sizes[0] / 64;     // 100,000 (< 2^17 for epk packing)
    const int* row = ei;
    const int* col = ei + E;
    const int P = (n + NPP - 1) / NPP;      // 196 (<= 256)
    const int B = (E + CHUNK - 1) / CHUNK;  // 391

    // workspace carve-up (256B aligned)
    char* ws = (char*)d_ws;
    size_t off = 0;
    auto alloc = [&](size_t bytes) -> void* {
        void* p = ws + off;
        off += (bytes + 255) & ~(size_t)255;
        return p;
    };
    int*      cntC = (int*)alloc((size_t)B * P * sizeof(int));
    int*      cntR = (int*)alloc((size_t)B * P * sizeof(int));
    int*      ptotC = (int*)alloc(256 * sizeof(int));
    int*      ptotR = (int*)alloc(256 * sizeof(int));
    int*      pofsC = (int*)alloc((256 + 1) * sizeof(int));
    int*      pofsR = (int*)alloc((256 + 1) * sizeof(int));
    float*    dinv = (float*)alloc((size_t)n * sizeof(float));
    int*      ofs  = (int*)alloc((size_t)(n + 1) * sizeof(int));
    int2*     bufC = (int2*)alloc((size_t)E * sizeof(int2));
    unsigned* bufR = (unsigned*)alloc((size_t)E * sizeof(unsigned));
    unsigned* epk  = (unsigned*)alloc((size_t)E * sizeof(unsigned));
    short*    hbA  = (short*)alloc((size_t)n * 64 * sizeof(short));
    short*    hbB  = (short*)alloc((size_t)n * 64 * sizeof(short));
    short*    t1b  = (short*)alloc((size_t)n * 64 * sizeof(short));
    short*    Ub   = (short*)alloc((size_t)n * 64 * sizeof(short));
    float*    S    = (float*)alloc((size_t)n * 32 * sizeof(float));
    short8_t* wpk1 = (short8_t*)alloc(1536 * sizeof(short8_t));
    short8_t* wpk2 = (short8_t*)alloc(1536 * sizeof(short8_t));
    short8_t* wpkm = (short8_t*)alloc(768 * sizeof(short8_t));
    short8_t* wpk4 = (short8_t*)alloc(192 * sizeof(short8_t));
    if (off > ws_size) return;  // fail loudly (validation) rather than corrupt

    // fused: bf16 copy of x + weight pre-pack + partition count
    const int initB = ceil_div_l((long)n * 16, 256);  // 6250
    init_count_kernel<<<initB + B, 256, 0, stream>>>(
        x, hbA, (long)n * 64, W1, W2, W3, W4, wpk1, wpk2, wpkm, wpk4,
        row, col, cntC, cntR, initB, P, B, E);

    // CSR build: colscan -> pscan -> scatter -> dinv -> fine (0 global atomics)
    colscan_kernel<<<2 * P, 256, 0, stream>>>(cntC, cntR, ptotC, ptotR, P, B);
    pscan_kernel<<<1, 256, 0, stream>>>(ptotC, ptotR, pofsC, pofsR, ofs, P, n, E);
    scatter_kernel<<<B, 256, 0, stream>>>(row, col, ew, cntC, cntR, pofsC, pofsR,
                                          bufC, bufR, P, E);
    dinv_kernel<<<P, 512, 0, stream>>>(bufR, pofsR, dinv, n);
    fine_csr_kernel<<<P, 512, 0, stream>>>(bufC, pofsC, dinv, ofs, epk, n);

    const int ab64 = ceil_div_l((long)n * 8, 256);
    const int ab32 = ceil_div_l((long)n * 4, 256);
    const int gb = ceil_div_l(n, 128);  // 782

    // Layer 1 (hbA = x): t1b = L@hbA; Ub = L@t1b; hbB = gemm
    agg_kernel<64><<<ab64, 256, 0, stream>>>(ofs, epk, hbA, t1b, n);
    agg_kernel<64><<<ab64, 256, 0, stream>>>(ofs, epk, t1b, Ub, n);
    gemm3_mfma<<<gb, 256, 0, stream>>>(hbA, t1b, Ub, wpk1, b1, hbB, n);

    // Layer 2: hbA = gemm(hbB, ...)
    agg_kernel<64><<<ab64, 256, 0, stream>>>(ofs, epk, hbB, t1b, n);
    agg_kernel<64><<<ab64, 256, 0, stream>>>(ofs, epk, t1b, Ub, n);
    gemm3_mfma<<<gb, 256, 0, stream>>>(hbB, t1b, Ub, wpk2, b2, hbA, n);

    // Layer 3 (64 -> 32), commute form, props in 32-dim:
    {
        short* P12b = t1b;
        short* Q1b  = Ub;
        short* Q2b  = Ub + (size_t)n * 32;
        short* hb3  = hbB;
        gemm_multi_mfma<<<gb, 256, 0, stream>>>(hbA, wpkm, b3, P12b, S, n);
        agg_dual_kernel<<<ab64, 256, 0, stream>>>(ofs, epk, P12b, Q1b, Q2b, n);
        agg_fin_kernel<<<ab32, 256, 0, stream>>>(ofs, epk, Q2b, S, Q1b, hb3, n);
    }

    // Layer 4 (32 -> 16): t1b32 = L@hb3; Ub32 = L@t1b32; d_out = gemm (fp32)
    agg_kernel<32><<<ab32, 256, 0, stream>>>(ofs, epk, hbB, t1b, n);
    agg_kernel<32><<<ab32, 256, 0, stream>>>(ofs, epk, t1b, Ub, n);
    gemm4_mfma<<<gb, 256, 0, stream>>>(hbB, t1b, Ub, wpk4, b4, (float*)d_out, n);
}

// Round 15
// 353.425 us; speedup vs baseline: 1.0945x; 1.0945x over previous
//
#include <hip/hip_runtime.h>
#include <math.h>

// ChebNet: 4 layers of ChebConv(K=3) + sigmoid.
// norm = -D^{-1/2} A D^{-1/2} (self loops removed)
// per layer: t1 = L@h ; U = L@t1 ; out = sigmoid(h@(W0-W2) + t1@W1 + U@(2*W2) + b)
//
// R1: atomic scatter -> CSR gather; 10.06ms -> 1.28ms
// R2: register-tiled gemm3, fused CSR build; -> 0.949ms
// R3: packed edges, layer-3 commute form; -> 0.823ms
// R4: bf16 gathers, t2 folded into weights; -> 0.660ms
// R5: two-level partition CSR build; -> 0.519ms
// R6: zero-global-atomic CSR build, bf16-only features; -> 0.494ms
// R7: all GEMMs -> MFMA; -> 0.397ms
// R8: REGRESSED (nt STORES write-through per-store, CHUNK 8192 starved).
// R9: revert; NPP 512; -> 0.397ms
// R10: XCD chunk swizzle + 4B packed epk; -> 0.360ms
// R11: REGRESSED (NPP 1024); reverted.
// R12: CHUNK 4096; -> 0.354ms
// R13: REGRESSED (nt LOADS evicted epk/bufC which are REUSED across passes).
// R14: revert nt loads (plain loads); keep init+count fusion only.

typedef __attribute__((ext_vector_type(8))) short short8_t;
typedef __attribute__((ext_vector_type(4))) short short4_t;
typedef __attribute__((ext_vector_type(4))) float f32x4;

#define NPP 512          // nodes per partition
#define FSH 9            // log2(NPP)
#define CHUNK 4096       // edges per block in count/scatter passes
#define NXCD 8

__device__ __forceinline__ float bf2f(short s) {
    return __int_as_float(((int)(unsigned short)s) << 16);
}
__device__ __forceinline__ short f2bf(float f) {  // round-to-nearest-even
    unsigned u = __float_as_uint(f);
    return (short)((u + 0x7FFFu + ((u >> 16) & 1u)) >> 16);
}

// Bijective blockIdx -> chunk map grouping consecutive chunks on one XCD
__device__ __forceinline__ int chunk_of_block(int bid, int B) {
    int xcd = bid & (NXCD - 1);
    int i = bid >> 3;
    int q = B >> 3, r = B & (NXCD - 1);
    return (xcd < r) ? xcd * (q + 1) + i : r * (q + 1) + (xcd - r) * q + i;
}

// edge decode: packed = (norm_top15 << 17) | src_row   (requires n < 2^17)
__device__ __forceinline__ int epk_row(unsigned u) { return (int)(u & 0x1FFFFu); }
__device__ __forceinline__ float epk_val(unsigned u) {
    return __uint_as_float((u >> 17) << 17);
}

// ---------------- init (x->bf16 + weight pre-pack) fused with count ----------------
// B-fragment layout for mfma_f32_16x16x32_bf16: lane holds B[k][col] with
// col = lane&15, k = (lane>>4)*8 + e.

__global__ __launch_bounds__(256) void init_count_kernel(
        const float* __restrict__ in, short* __restrict__ out, long m,
        const float* __restrict__ W1, const float* __restrict__ W2,
        const float* __restrict__ W3, const float* __restrict__ W4,
        short8_t* __restrict__ wpk1, short8_t* __restrict__ wpk2,
        short8_t* __restrict__ wpkm, short8_t* __restrict__ wpk4,
        const int* __restrict__ row, const int* __restrict__ col,
        int* __restrict__ cntC, int* __restrict__ cntR,
        int initB, int P, int B, int E) {
    __shared__ int hc[2][256], hr[2][256];
    if (blockIdx.x >= initB) {
        // ---- count branch ----
        int cbid = blockIdx.x - initB;
        for (int i = threadIdx.x; i < P; i += 256) {
            hc[0][i] = 0; hc[1][i] = 0; hr[0][i] = 0; hr[1][i] = 0;
        }
        __syncthreads();
        int chunk = chunk_of_block(cbid, B);
        int cp = threadIdx.x & 1;
        int base = chunk * CHUNK;
        int lim = min(E, base + CHUNK);
        for (int e = base + threadIdx.x; e < lim; e += 256) {
            atomicAdd(&hc[cp][col[e] >> FSH], 1);
            atomicAdd(&hr[cp][row[e] >> FSH], 1);
        }
        __syncthreads();
        long o = (long)chunk * P;
        for (int i = threadIdx.x; i < P; i += 256) {
            cntC[o + i] = hc[0][i] + hc[1][i];
            cntR[o + i] = hr[0][i] + hr[1][i];
        }
        return;
    }
    // ---- init branch ----
    long gi = (long)blockIdx.x * 256 + threadIdx.x;
    long i4 = gi * 4;
    if (i4 < m) {
        float4 v = *reinterpret_cast<const float4*>(in + i4);
        short4_t s;
        s[0] = f2bf(v.x); s[1] = f2bf(v.y); s[2] = f2bf(v.z); s[3] = f2bf(v.w);
        *reinterpret_cast<short4_t*>(out + i4) = s;
    }
    int idx = (int)gi;
    if (idx >= 4032) return;
    short8_t o;
    if (idx < 3072) {  // gemm3 packs for W1 / W2 (64->64)
        const float* W = (idx < 1536) ? W1 : W2;
        int f = (idx < 1536) ? idx : idx - 1536;
        int lane = f & 63, ct = (f >> 6) & 3, s = f >> 8;
        int li = lane & 15, lg = lane >> 4;
        int p = s >> 1;
        int cidx = ct * 16 + li;
#pragma unroll
        for (int e = 0; e < 8; ++e) {
            int k = (s & 1) * 32 + lg * 8 + e;
            int base = k * 64 + cidx;
            float v = (p == 0) ? W[base] - W[8192 + base]
                    : (p == 1) ? W[4096 + base]
                               : 2.0f * W[8192 + base];
            o[e] = f2bf(v);
        }
        ((idx < 1536) ? wpk1 : wpk2)[f] = o;
    } else if (idx < 3840) {  // gemm_multi pack for W3 (64->3x32)
        int f = idx - 3072;
        int lane = f & 63, q = f >> 6;
        int s = q / 6, ct = q % 6;
        int li = lane & 15, lg = lane >> 4;
        int g = ct >> 1;
        int cl = (ct & 1) * 16 + li;
#pragma unroll
        for (int e = 0; e < 8; ++e) {
            int k = s * 32 + lg * 8 + e;
            int base = k * 32 + cl;
            float v = (g == 0) ? W3[base] - W3[4096 + base]
                    : (g == 1) ? W3[2048 + base]
                               : W3[4096 + base];
            o[e] = f2bf(v);
        }
        wpkm[f] = o;
    } else {  // gemm4 pack for W4 (32->16)
        int f = idx - 3840;
        int lane = f & 63, s = f >> 6;
        int li = lane & 15, lg = lane >> 4;
#pragma unroll
        for (int e = 0; e < 8; ++e) {
            int k = lg * 8 + e;
            int base = k * 16 + li;
            float v = (s == 0) ? W4[base] - W4[1024 + base]
                    : (s == 1) ? W4[512 + base]
                               : 2.0f * W4[1024 + base];
            o[e] = f2bf(v);
        }
        wpk4[f] = o;
    }
}

// ---------------- CSR build (zero global atomics) ----------------

__global__ __launch_bounds__(256) void colscan_kernel(
        int* __restrict__ cntC, int* __restrict__ cntR,
        int* __restrict__ ptotC, int* __restrict__ ptotR, int P, int B) {
    int bid = blockIdx.x;
    int* m; int* ptot; int p;
    if (bid < P) { m = cntC; ptot = ptotC; p = bid; }
    else         { m = cntR; ptot = ptotR; p = bid - P; }
    __shared__ int sh[256];
    int run = 0;
    for (int b0 = 0; b0 < B; b0 += 256) {
        int b = b0 + threadIdx.x;
        int v = (b < B) ? m[(long)b * P + p] : 0;
        sh[threadIdx.x] = v;
        __syncthreads();
        for (int o = 1; o < 256; o <<= 1) {
            int t = (threadIdx.x >= o) ? sh[threadIdx.x - o] : 0;
            __syncthreads();
            sh[threadIdx.x] += t;
            __syncthreads();
        }
        if (b < B) m[(long)b * P + p] = run + sh[threadIdx.x] - v;
        run += sh[255];
        __syncthreads();
    }
    if (threadIdx.x == 0) ptot[p] = run;
}

__global__ __launch_bounds__(256) void pscan_kernel(
        const int* __restrict__ ptotC, const int* __restrict__ ptotR,
        int* __restrict__ pofsC, int* __restrict__ pofsR,
        int* __restrict__ ofs, int P, int n, int E) {
    __shared__ int sh[256];
    int tid = threadIdx.x;
    int v = (tid < P) ? ptotC[tid] : 0;
    sh[tid] = v;
    __syncthreads();
    for (int o = 1; o < 256; o <<= 1) {
        int t = (tid >= o) ? sh[tid - o] : 0;
        __syncthreads();
        sh[tid] += t;
        __syncthreads();
    }
    if (tid < P) pofsC[tid] = sh[tid] - v;
    if (tid == 0) pofsC[P] = E;
    __syncthreads();
    v = (tid < P) ? ptotR[tid] : 0;
    sh[tid] = v;
    __syncthreads();
    for (int o = 1; o < 256; o <<= 1) {
        int t = (tid >= o) ? sh[tid - o] : 0;
        __syncthreads();
        sh[tid] += t;
        __syncthreads();
    }
    if (tid < P) pofsR[tid] = sh[tid] - v;
    if (tid == 0) { pofsR[P] = E; ofs[n] = E; }
}

// bufC: (finec(9b) << 23 | row(23b), w_bits)   bufR: finer(9b)<<23 | (w>>9)

__global__ __launch_bounds__(256) void scatter_kernel(
        const int* __restrict__ row, const int* __restrict__ col,
        const float* __restrict__ ew,
        const int* __restrict__ cntC, const int* __restrict__ cntR,
        const int* __restrict__ pofsC, const int* __restrict__ pofsR,
        int2* __restrict__ bufC, unsigned* __restrict__ bufR, int P, int E) {
    __shared__ int hc[256], hr[256];
    int chunk = chunk_of_block(blockIdx.x, gridDim.x);
    long o = (long)chunk * P;
    for (int i = threadIdx.x; i < P; i += 256) {
        hc[i] = pofsC[i] + cntC[o + i];
        hr[i] = pofsR[i] + cntR[o + i];
    }
    __syncthreads();
    int base = chunk * CHUNK;
    int lim = min(E, base + CHUNK);
    for (int e = base + threadIdx.x; e < lim; e += 256) {
        int r = row[e], c = col[e];
        float w = (r == c) ? 0.0f : ew[e];
        unsigned wb = __float_as_uint(w);
        int pc = atomicAdd(&hc[c >> FSH], 1);
        bufC[pc] = make_int2((int)(((unsigned)(c & (NPP - 1)) << 23) | (unsigned)r), (int)wb);
        int pr = atomicAdd(&hr[r >> FSH], 1);
        bufR[pr] = ((unsigned)(r & (NPP - 1)) << 23) | (wb >> 9);
    }
}

__global__ __launch_bounds__(512) void dinv_kernel(
        const unsigned* __restrict__ bufR, const int* __restrict__ rofs,
        float* __restrict__ dinv, int n) {
    int p = blockIdx.x;
    __shared__ float s[NPP];
    s[threadIdx.x] = 0.0f;
    __syncthreads();
    int beg = rofs[p], end = rofs[p + 1];
    for (int k = beg + threadIdx.x; k < end; k += 512) {
        unsigned u = bufR[k];
        atomicAdd(&s[u >> 23], __uint_as_float((u & 0x7FFFFFu) << 9));
    }
    __syncthreads();
    int node = (p << FSH) + threadIdx.x;
    if (node < n) {
        float d = s[threadIdx.x];
        dinv[node] = d > 0.0f ? rsqrtf(d) : 0.0f;
    }
}

__global__ __launch_bounds__(512) void fine_csr_kernel(
        const int2* __restrict__ bufC, const int* __restrict__ pofs,
        const float* __restrict__ dinv, int* __restrict__ ofs,
        unsigned* __restrict__ epk, int n) {
    int p = blockIdx.x;
    int tid = threadIdx.x;
    __shared__ int hist[NPP];
    __shared__ int sc[NPP];
    __shared__ float dc[NPP];
    hist[tid] = 0;
    int node = (p << FSH) + tid;
    dc[tid] = (node < n) ? dinv[node] : 0.0f;
    __syncthreads();
    int beg = pofs[p], end = pofs[p + 1];
    for (int k = beg + tid; k < end; k += 512)
        atomicAdd(&hist[((unsigned)bufC[k].x) >> 23], 1);
    __syncthreads();
    int v = hist[tid];
    sc[tid] = v;
    __syncthreads();
    for (int o = 1; o < 512; o <<= 1) {
        int t = (tid >= o) ? sc[tid - o] : 0;
        __syncthreads();
        sc[tid] += t;
        __syncthreads();
    }
    int mybase = beg + sc[tid] - v;  // exclusive
    if (node < n) ofs[node] = mybase;
    hist[tid] = mybase;  // becomes cursor
    __syncthreads();
    for (int k = beg + tid; k < end; k += 512) {
        int2 ed = bufC[k];
        unsigned key = (unsigned)ed.x;
        int fc = key >> 23;
        int r = (int)(key & 0x7FFFFFu);
        float w = __int_as_float(ed.y);
        float nrm = -dinv[r] * w * dc[fc];
        unsigned nb = __float_as_uint(nrm);
        unsigned n15 = (nb + 0xFFFFu + ((nb >> 17) & 1u)) >> 17;  // RNE top-15
        int pos = atomicAdd(&hist[fc], 1);
        epk[pos] = (n15 << 17) | (unsigned)r;  // requires n < 2^17
    }
}

// ---------------- aggregation (bf16 gather, fp32 accumulate, bf16 out) ----------------

template <int D>
__global__ __launch_bounds__(256) void agg_kernel(
        const int* __restrict__ ofs, const unsigned* __restrict__ epk,
        const short* __restrict__ tb, short* __restrict__ outb, int n) {
    constexpr int LPN = D / 8;
    int idx = blockIdx.x * 256 + threadIdx.x;
    int node = idx / LPN;
    int l = idx % LPN;
    if (node >= n) return;
    int beg = ofs[node], end = ofs[node + 1];
    float a[8] = {0.f, 0.f, 0.f, 0.f, 0.f, 0.f, 0.f, 0.f};
    const short* tc = tb + l * 8;
    int k = beg;
    for (; k + 8 <= end; k += 8) {
        unsigned ev[8];
        short8_t xv[8];
#pragma unroll
        for (int u = 0; u < 8; ++u) ev[u] = epk[k + u];
#pragma unroll
        for (int u = 0; u < 8; ++u)
            xv[u] = *reinterpret_cast<const short8_t*>(tc + (long)epk_row(ev[u]) * D);
#pragma unroll
        for (int u = 0; u < 8; ++u) {
            float v = epk_val(ev[u]);
#pragma unroll
            for (int j = 0; j < 8; ++j) a[j] = fmaf(v, bf2f(xv[u][j]), a[j]);
        }
    }
    for (; k + 4 <= end; k += 4) {
        unsigned ev[4];
        short8_t xv[4];
#pragma unroll
        for (int u = 0; u < 4; ++u) ev[u] = epk[k + u];
#pragma unroll
        for (int u = 0; u < 4; ++u)
            xv[u] = *reinterpret_cast<const short8_t*>(tc + (long)epk_row(ev[u]) * D);
#pragma unroll
        for (int u = 0; u < 4; ++u) {
            float v = epk_val(ev[u]);
#pragma unroll
            for (int j = 0; j < 8; ++j) a[j] = fmaf(v, bf2f(xv[u][j]), a[j]);
        }
    }
    for (; k < end; ++k) {
        unsigned e0 = epk[k];
        short8_t x0 = *reinterpret_cast<const short8_t*>(tc + (long)epk_row(e0) * D);
        float v = epk_val(e0);
#pragma unroll
        for (int j = 0; j < 8; ++j) a[j] = fmaf(v, bf2f(x0[j]), a[j]);
    }
    short8_t s;
#pragma unroll
    for (int j = 0; j < 8; ++j) s[j] = f2bf(a[j]);
    *reinterpret_cast<short8_t*>(outb + (long)node * D + l * 8) = s;
}

// Dual agg for layer 3: tb [n][64] = [P1|P2] bf16; lanes 0-3 -> Q1b, 4-7 -> Q2b.

__global__ __launch_bounds__(256) void agg_dual_kernel(
        const int* __restrict__ ofs, const unsigned* __restrict__ epk,
        const short* __restrict__ tb, short* __restrict__ Q1b,
        short* __restrict__ Q2b, int n) {
    int idx = blockIdx.x * 256 + threadIdx.x;
    int node = idx >> 3;
    int l = idx & 7;
    if (node >= n) return;
    int beg = ofs[node], end = ofs[node + 1];
    float a[8] = {0.f, 0.f, 0.f, 0.f, 0.f, 0.f, 0.f, 0.f};
    const short* tc = tb + l * 8;
    int k = beg;
    for (; k + 8 <= end; k += 8) {
        unsigned ev[8];
        short8_t xv[8];
#pragma unroll
        for (int u = 0; u < 8; ++u) ev[u] = epk[k + u];
#pragma unroll
        for (int u = 0; u < 8; ++u)
            xv[u] = *reinterpret_cast<const short8_t*>(tc + (long)epk_row(ev[u]) * 64);
#pragma unroll
        for (int u = 0; u < 8; ++u) {
            float v = epk_val(ev[u]);
#pragma unroll
            for (int j = 0; j < 8; ++j) a[j] = fmaf(v, bf2f(xv[u][j]), a[j]);
        }
    }
    for (; k + 4 <= end; k += 4) {
        unsigned ev[4];
        short8_t xv[4];
#pragma unroll
        for (int u = 0; u < 4; ++u) ev[u] = epk[k + u];
#pragma unroll
        for (int u = 0; u < 4; ++u)
            xv[u] = *reinterpret_cast<const short8_t*>(tc + (long)epk_row(ev[u]) * 64);
#pragma unroll
        for (int u = 0; u < 4; ++u) {
            float v = epk_val(ev[u]);
#pragma unroll
            for (int j = 0; j < 8; ++j) a[j] = fmaf(v, bf2f(xv[u][j]), a[j]);
        }
    }
    for (; k < end; ++k) {
        unsigned e0 = epk[k];
        short8_t x0 = *reinterpret_cast<const short8_t*>(tc + (long)epk_row(e0) * 64);
        float v = epk_val(e0);
#pragma unroll
        for (int j = 0; j < 8; ++j) a[j] = fmaf(v, bf2f(x0[j]), a[j]);
    }
    short* ob = (l < 4) ? Q1b : Q2b;
    long o = (long)node * 32 + (l & 3) * 8;
    short8_t s;
#pragma unroll
    for (int j = 0; j < 8; ++j) s[j] = f2bf(a[j]);
    *reinterpret_cast<short8_t*>(ob + o) = s;
}

// Final layer-3 agg: acc = L@Q2 gather; out = sigmoid(S + Q1 + 2*acc) (bf16).

__global__ __launch_bounds__(256) void agg_fin_kernel(
        const int* __restrict__ ofs, const unsigned* __restrict__ epk,
        const short* __restrict__ Q2b, const float* __restrict__ S,
        const short* __restrict__ Q1b, short* __restrict__ outb, int n) {
    int idx = blockIdx.x * 256 + threadIdx.x;
    int node = idx >> 2;
    int l = idx & 3;
    if (node >= n) return;
    int beg = ofs[node], end = ofs[node + 1];
    float a[8] = {0.f, 0.f, 0.f, 0.f, 0.f, 0.f, 0.f, 0.f};
    const short* tc = Q2b + l * 8;
    int k = beg;
    for (; k + 4 <= end; k += 4) {
        unsigned ev[4];
        short8_t xv[4];
#pragma unroll
        for (int u = 0; u < 4; ++u) ev[u] = epk[k + u];
#pragma unroll
        for (int u = 0; u < 4; ++u)
            xv[u] = *reinterpret_cast<const short8_t*>(tc + (long)epk_row(ev[u]) * 32);
#pragma unroll
        for (int u = 0; u < 4; ++u) {
            float v = epk_val(ev[u]);
#pragma unroll
            for (int j = 0; j < 8; ++j) a[j] = fmaf(v, bf2f(xv[u][j]), a[j]);
        }
    }
    for (; k < end; ++k) {
        unsigned e0 = epk[k];
        short8_t x0 = *reinterpret_cast<const short8_t*>(tc + (long)epk_row(e0) * 32);
        float v = epk_val(e0);
#pragma unroll
        for (int j = 0; j < 8; ++j) a[j] = fmaf(v, bf2f(x0[j]), a[j]);
    }
    long o = (long)node * 32 + l * 8;
    float4 s0 = *reinterpret_cast<const float4*>(S + o);
    float4 s1 = *reinterpret_cast<const float4*>(S + o + 4);
    short8_t q1 = *reinterpret_cast<const short8_t*>(Q1b + o);
    float sv[8] = {s0.x, s0.y, s0.z, s0.w, s1.x, s1.y, s1.z, s1.w};
    short8_t r;
#pragma unroll
    for (int j = 0; j < 8; ++j) {
        float z = sv[j] + bf2f(q1[j]) + 2.0f * a[j];
        r[j] = f2bf(1.0f / (1.0f + expf(-z)));
    }
    *reinterpret_cast<short8_t*>(outb + o) = r;
}

// ---------------- MFMA GEMMs ----------------

__global__ __launch_bounds__(256) void gemm3_mfma(
        const short* __restrict__ t0b, const short* __restrict__ t1b,
        const short* __restrict__ t2b, const short8_t* __restrict__ wpk,
        const float* __restrict__ b, short* __restrict__ outb, int n) {
    const int tid = threadIdx.x;
    const int wave = tid >> 6;
    const int lane = tid & 63;
    const int li = lane & 15;
    const int lg = lane >> 4;

    short8_t bfr[6][4];
#pragma unroll
    for (int s = 0; s < 6; ++s)
#pragma unroll
        for (int ct = 0; ct < 4; ++ct)
            bfr[s][ct] = wpk[(s * 4 + ct) * 64 + lane];

    float bias_v[4];
#pragma unroll
    for (int ct = 0; ct < 4; ++ct) bias_v[ct] = b[ct * 16 + li];

#pragma unroll
    for (int t = 0; t < 2; ++t) {
        int r0 = blockIdx.x * 128 + wave * 32 + t * 16;
        if (r0 >= n) continue;
        int rA = r0 + li;
        if (rA >= n) rA = n - 1;
        f32x4 acc[4] = {{0.f, 0.f, 0.f, 0.f}, {0.f, 0.f, 0.f, 0.f},
                        {0.f, 0.f, 0.f, 0.f}, {0.f, 0.f, 0.f, 0.f}};
#pragma unroll
        for (int s = 0; s < 6; ++s) {
            const short* src = (s < 2) ? t0b : (s < 4) ? t1b : t2b;
            int k = (s & 1) * 32 + lg * 8;
            short8_t a = *reinterpret_cast<const short8_t*>(src + (long)rA * 64 + k);
#pragma unroll
            for (int ct = 0; ct < 4; ++ct)
                acc[ct] = __builtin_amdgcn_mfma_f32_16x16x32_bf16(a, bfr[s][ct], acc[ct], 0, 0, 0);
        }
#pragma unroll
        for (int ct = 0; ct < 4; ++ct) {
#pragma unroll
            for (int reg = 0; reg < 4; ++reg) {
                int row = r0 + lg * 4 + reg;
                if (row < n) {
                    float z = acc[ct][reg] + bias_v[ct];
                    float res = 1.0f / (1.0f + expf(-z));
                    outb[(long)row * 64 + ct * 16 + li] = f2bf(res);
                }
            }
        }
    }
}

__global__ __launch_bounds__(256) void gemm_multi_mfma(
        const short* __restrict__ hb, const short8_t* __restrict__ wpk,
        const float* __restrict__ b, short* __restrict__ P12b,
        float* __restrict__ S, int n) {
    const int tid = threadIdx.x;
    const int wave = tid >> 6;
    const int lane = tid & 63;
    const int li = lane & 15;
    const int lg = lane >> 4;

    short8_t bfr[2][6];
#pragma unroll
    for (int s = 0; s < 2; ++s)
#pragma unroll
        for (int ct = 0; ct < 6; ++ct)
            bfr[s][ct] = wpk[(s * 6 + ct) * 64 + lane];

    float bS0 = b[li], bS1 = b[16 + li];

#pragma unroll
    for (int t = 0; t < 2; ++t) {
        int r0 = blockIdx.x * 128 + wave * 32 + t * 16;
        if (r0 >= n) continue;
        int rA = r0 + li;
        if (rA >= n) rA = n - 1;
        f32x4 acc[6] = {{0.f, 0.f, 0.f, 0.f}, {0.f, 0.f, 0.f, 0.f},
                        {0.f, 0.f, 0.f, 0.f}, {0.f, 0.f, 0.f, 0.f},
                        {0.f, 0.f, 0.f, 0.f}, {0.f, 0.f, 0.f, 0.f}};
#pragma unroll
        for (int s = 0; s < 2; ++s) {
            int k = s * 32 + lg * 8;
            short8_t a = *reinterpret_cast<const short8_t*>(hb + (long)rA * 64 + k);
#pragma unroll
            for (int ct = 0; ct < 6; ++ct)
                acc[ct] = __builtin_amdgcn_mfma_f32_16x16x32_bf16(a, bfr[s][ct], acc[ct], 0, 0, 0);
        }
#pragma unroll
        for (int ct = 0; ct < 6; ++ct) {
            int g = ct >> 1;
            int cl = (ct & 1) * 16 + li;
#pragma unroll
            for (int reg = 0; reg < 4; ++reg) {
                int row = r0 + lg * 4 + reg;
                if (row >= n) continue;
                float v = acc[ct][reg];
                if (g == 0) {
                    S[(long)row * 32 + cl] = v + ((ct & 1) ? bS1 : bS0);
                } else if (g == 1) {
                    P12b[(long)row * 64 + cl] = f2bf(v);
                } else {
                    P12b[(long)row * 64 + 32 + cl] = f2bf(v);
                }
            }
        }
    }
}

__global__ __launch_bounds__(256) void gemm4_mfma(
        const short* __restrict__ t0b, const short* __restrict__ t1b,
        const short* __restrict__ t2b, const short8_t* __restrict__ wpk,
        const float* __restrict__ b, float* __restrict__ out, int n) {
    const int tid = threadIdx.x;
    const int wave = tid >> 6;
    const int lane = tid & 63;
    const int li = lane & 15;
    const int lg = lane >> 4;

    short8_t bfr[3];
#pragma unroll
    for (int s = 0; s < 3; ++s) bfr[s] = wpk[s * 64 + lane];

    float bias_v = b[li];

#pragma unroll
    for (int t = 0; t < 2; ++t) {
        int r0 = blockIdx.x * 128 + wave * 32 + t * 16;
        if (r0 >= n) continue;
        int rA = r0 + li;
        if (rA >= n) rA = n - 1;
        f32x4 acc = {0.f, 0.f, 0.f, 0.f};
        int k = lg * 8;
        short8_t a0 = *reinterpret_cast<const short8_t*>(t0b + (long)rA * 32 + k);
        acc = __builtin_amdgcn_mfma_f32_16x16x32_bf16(a0, bfr[0], acc, 0, 0, 0);
        short8_t a1 = *reinterpret_cast<const short8_t*>(t1b + (long)rA * 32 + k);
        acc = __builtin_amdgcn_mfma_f32_16x16x32_bf16(a1, bfr[1], acc, 0, 0, 0);
        short8_t a2 = *reinterpret_cast<const short8_t*>(t2b + (long)rA * 32 + k);
        acc = __builtin_amdgcn_mfma_f32_16x16x32_bf16(a2, bfr[2], acc, 0, 0, 0);
#pragma unroll
        for (int reg = 0; reg < 4; ++reg) {
            int row = r0 + lg * 4 + reg;
            if (row < n) {
                float z = acc[reg] + bias_v;
                out[(long)row * 16 + li] = 1.0f / (1.0f + expf(-z));
            }
        }
    }
}

// ---------------- host side ----------------

static inline int ceil_div_l(long a, long b) { return (int)((a + b - 1) / b); }

extern "C" void kernel_launch(void* const* d_in, const int* in_sizes, int n_in,
                              void* d_out, int out_size, void* d_ws, size_t ws_size,
                              hipStream_t stream) {
    const float* x  = (const float*)d_in[0];
    const int*   ei = (const int*)d_in[1];
    const float* ew = (const float*)d_in[2];
    const float* W1 = (const float*)d_in[3];  const float* b1 = (const float*)d_in[4];
    const float* W2 = (const float*)d_in[5];  const float* b2 = (const float*)d_in[6];
    const float* W3 = (const float*)d_in[7];  const float* b3 = (const float*)d_in[8];
    const float* W4 = (const float*)d_in[9];  const float* b4 = (const float*)d_in[10];

    const int E = in_sizes[2];          // 1,600,000
    const int n = in_sizes[0] / 64;     // 100,000 (< 2^17 for epk packing)
    const int* row = ei;
    const int* col = ei + E;
    const int P = (n + NPP - 1) / NPP;      // 196 (<= 256)
    const int B = (E + CHUNK - 1) / CHUNK;  // 391

    // workspace carve-up (256B aligned)
    char* ws = (char*)d_ws;
    size_t off = 0;
    auto alloc = [&](size_t bytes) -> void* {
        void* p = ws + off;
        off += (bytes + 255) & ~(size_t)255;
        return p;
    };
    int*      cntC = (int*)alloc((size_t)B * P * sizeof(int));
    int*      cntR = (int*)alloc((size_t)B * P * sizeof(int));
    int*      ptotC = (int*)alloc(256 * sizeof(int));
    int*      ptotR = (int*)alloc(256 * sizeof(int));
    int*      pofsC = (int*)alloc((256 + 1) * sizeof(int));
    int*      pofsR = (int*)alloc((256 + 1) * sizeof(int));
    float*    dinv = (float*)alloc((size_t)n * sizeof(float));
    int*      ofs  = (int*)alloc((size_t)(n + 1) * sizeof(int));
    int2*     bufC = (int2*)alloc((size_t)E * sizeof(int2));
    unsigned* bufR = (unsigned*)alloc((size_t)E * sizeof(unsigned));
    unsigned* epk  = (unsigned*)alloc((size_t)E * sizeof(unsigned));
    short*    hbA  = (short*)alloc((size_t)n * 64 * sizeof(short));
    short*    hbB  = (short*)alloc((size_t)n * 64 * sizeof(short));
    short*    t1b  = (short*)alloc((size_t)n * 64 * sizeof(short));
    short*    Ub   = (short*)alloc((size_t)n * 64 * sizeof(short));
    float*    S    = (float*)alloc((size_t)n * 32 * sizeof(float));
    short8_t* wpk1 = (short8_t*)alloc(1536 * sizeof(short8_t));
    short8_t* wpk2 = (short8_t*)alloc(1536 * sizeof(short8_t));
    short8_t* wpkm = (short8_t*)alloc(768 * sizeof(short8_t));
    short8_t* wpk4 = (short8_t*)alloc(192 * sizeof(short8_t));
    if (off > ws_size) return;  // fail loudly (validation) rather than corrupt

    // fused: bf16 copy of x + weight pre-pack + partition count
    const int initB = ceil_div_l((long)n * 16, 256);  // 6250
    init_count_kernel<<<initB + B, 256, 0, stream>>>(
        x, hbA, (long)n * 64, W1, W2, W3, W4, wpk1, wpk2, wpkm, wpk4,
        row, col, cntC, cntR, initB, P, B, E);

    // CSR build: colscan -> pscan -> scatter -> dinv -> fine (0 global atomics)
    colscan_kernel<<<2 * P, 256, 0, stream>>>(cntC, cntR, ptotC, ptotR, P, B);
    pscan_kernel<<<1, 256, 0, stream>>>(ptotC, ptotR, pofsC, pofsR, ofs, P, n, E);
    scatter_kernel<<<B, 256, 0, stream>>>(row, col, ew, cntC, cntR, pofsC, pofsR,
                                          bufC, bufR, P, E);
    dinv_kernel<<<P, 512, 0, stream>>>(bufR, pofsR, dinv, n);
    fine_csr_kernel<<<P, 512, 0, stream>>>(bufC, pofsC, dinv, ofs, epk, n);

    const int ab64 = ceil_div_l((long)n * 8, 256);
    const int ab32 = ceil_div_l((long)n * 4, 256);
    const int gb = ceil_div_l(n, 128);  // 782

    // Layer 1 (hbA = x): t1b = L@hbA; Ub = L@t1b; hbB = gemm
    agg_kernel<64><<<ab64, 256, 0, stream>>>(ofs, epk, hbA, t1b, n);
    agg_kernel<64><<<ab64, 256, 0, stream>>>(ofs, epk, t1b, Ub, n);
    gemm3_mfma<<<gb, 256, 0, stream>>>(hbA, t1b, Ub, wpk1, b1, hbB, n);

    // Layer 2: hbA = gemm(hbB, ...)
    agg_kernel<64><<<ab64, 256, 0, stream>>>(ofs, epk, hbB, t1b, n);
    agg_kernel<64><<<ab64, 256, 0, stream>>>(ofs, epk, t1b, Ub, n);
    gemm3_mfma<<<gb, 256, 0, stream>>>(hbB, t1b, Ub, wpk2, b2, hbA, n);

    // Layer 3 (64 -> 32), commute form, props in 32-dim:
    {
        short* P12b = t1b;
        short* Q1b  = Ub;
        short* Q2b  = Ub + (size_t)n * 32;
        short* hb3  = hbB;
        gemm_multi_mfma<<<gb, 256, 0, stream>>>(hbA, wpkm, b3, P12b, S, n);
        agg_dual_kernel<<<ab64, 256, 0, stream>>>(ofs, epk, P12b, Q1b, Q2b, n);
        agg_fin_kernel<<<ab32, 256, 0, stream>>>(ofs, epk, Q2b, S, Q1b, hb3, n);
    }

    // Layer 4 (32 -> 16): t1b32 = L@hb3; Ub32 = L@t1b32; d_out = gemm (fp32)
    agg_kernel<32><<<ab32, 256, 0, stream>>>(ofs, epk, hbB, t1b, n);
    agg_kernel<32><<<ab32, 256, 0, stream>>>(ofs, epk, t1b, Ub, n);
    gemm4_mfma<<<gb, 256, 0, stream>>>(hbB, t1b, Ub, wpk4, b4, (float*)d_out, n);
}